// Round 3
// baseline (43.715 us; speedup 1.0000x reference)
//
#include <hip/hip_runtime.h>
#include <math.h>

#define DIM 1024
#define D4  (DIM / 4)      // 256 float4 per row
#define SNUM 5
#define EPSL 1e-6f
#define MARGINL 1.0f
#define ANCH_PER_BLK 4     // 4 waves/block, one wave per anchor
#define FIXSCALE 4294967296.0  // 2^32

__device__ __forceinline__ float sq4(const float4& x, const float4& y) {
    float dx = x.x - y.x + EPSL;
    float dy = x.y - y.y + EPSL;
    float dz = x.z - y.z + EPSL;
    float dw = x.w - y.w + EPSL;
    return dx * dx + dy * dy + dz * dz + dw * dw;
}

// One wave (64 lanes) per anchor; lane l owns float4 slots {l, l+64, l+128, l+192}.
// 11 distance partials accumulated in registers over the 4 slices, reduced with a
// single 6-step butterfly per wave. Block partial hinge-sum is atomically added in
// fixed point (deterministic); the last block converts to the float mean.
__global__ __launch_bounds__(256) void hinge_kernel(const float* __restrict__ vfeat,
                                                    const float* __restrict__ afeat,
                                                    unsigned long long* __restrict__ sum_fx,
                                                    unsigned int* __restrict__ done_ctr,
                                                    float* __restrict__ out,
                                                    int B, int nblocks) {
    // XCD-chunked bijective swizzle on block index: each XCD owns a contiguous
    // anchor range so neighbor rows k+1..k+5 stay in its L2.
    int b = blockIdx.x;
    if ((nblocks & 7) == 0) {
        const int chunk = nblocks >> 3;
        b = (b & 7) * chunk + (b >> 3);
    }
    const int wave = threadIdx.x >> 6;
    const int lane = threadIdx.x & 63;
    const int k = b * ANCH_PER_BLK + wave;

    const float4* __restrict__ v4 = reinterpret_cast<const float4*>(vfeat);
    const float4* __restrict__ a4 = reinterpret_cast<const float4*>(afeat);

    // own-row slices (4 float4 each, stride 64)
    float4 vk[4], ak[4];
    #pragma unroll
    for (int s = 0; s < 4; ++s) {
        vk[s] = v4[(size_t)k * D4 + s * 64 + lane];
        ak[s] = a4[(size_t)k * D4 + s * 64 + lane];
    }

    float acc[11];
    acc[0] = 0.0f;
    #pragma unroll
    for (int s = 0; s < 4; ++s) acc[0] += sq4(vk[s], ak[s]);

    #pragma unroll
    for (int m = 0; m < SNUM; ++m) {
        int j = (m + k + 1) % B;
        if (m == k) j = (k + 1) % B;
        float s1 = 0.0f, s2 = 0.0f;
        #pragma unroll
        for (int s = 0; s < 4; ++s) {
            const float4 aj = a4[(size_t)j * D4 + s * 64 + lane];
            const float4 vj = v4[(size_t)j * D4 + s * 64 + lane];
            s1 += sq4(vk[s], aj);
            s2 += sq4(ak[s], vj);
        }
        acc[1 + m]        = s1;
        acc[1 + SNUM + m] = s2;
    }

    // 64-lane butterfly reduction of all 11 partials
    #pragma unroll
    for (int off = 32; off > 0; off >>= 1) {
        #pragma unroll
        for (int i = 0; i < 11; ++i)
            acc[i] += __shfl_xor(acc[i], off, 64);
    }

    __shared__ float sh[ANCH_PER_BLK];
    if (lane == 0) {
        const float d_p = sqrtf(acc[0]);
        float dn1 = sqrtf(acc[1]);
        float dn2 = sqrtf(acc[1 + SNUM]);
        #pragma unroll
        for (int m = 1; m < SNUM; ++m) {
            dn1 = fminf(dn1, sqrtf(acc[1 + m]));
            dn2 = fminf(dn2, sqrtf(acc[1 + SNUM + m]));
        }
        sh[wave] = fmaxf(MARGINL + 2.0f * d_p - dn1 - dn2, 0.0f);
    }
    __syncthreads();

    if (threadIdx.x == 0) {
        float bsum = 0.0f;
        #pragma unroll
        for (int w = 0; w < ANCH_PER_BLK; ++w) bsum += sh[w];
        // deterministic fixed-point accumulate (integer adds commute exactly)
        unsigned long long fx = (unsigned long long)((double)bsum * FIXSCALE + 0.5);
        atomicAdd(sum_fx, fx);
        __threadfence();
        unsigned int old = atomicAdd(done_ctr, 1u);
        if (old == (unsigned int)(nblocks - 1)) {
            unsigned long long total = atomicAdd(sum_fx, 0ull);  // coherent read
            out[0] = (float)(((double)total / FIXSCALE) / (double)B);
        }
    }
}

extern "C" void kernel_launch(void* const* d_in, const int* in_sizes, int n_in,
                              void* d_out, int out_size, void* d_ws, size_t ws_size,
                              hipStream_t stream) {
    const float* vfeat = (const float*)d_in[0];
    const float* afeat = (const float*)d_in[1];
    const int B = in_sizes[0] / DIM;
    const int nblocks = B / ANCH_PER_BLK;

    unsigned long long* sum_fx = (unsigned long long*)d_ws;
    unsigned int* done_ctr = (unsigned int*)((char*)d_ws + 8);
    float* out = (float*)d_out;

    // zero the 16-byte accumulator region each call (graph-capturable memset node)
    hipMemsetAsync(d_ws, 0, 16, stream);

    hinge_kernel<<<nblocks, 256, 0, stream>>>(vfeat, afeat, sum_fx, done_ctr, out,
                                              B, nblocks);
}

// Round 4
// 43.423 us; speedup vs baseline: 1.0067x; 1.0067x over previous
//
#include <hip/hip_runtime.h>
#include <math.h>

#define DIM 1024
#define D4  (DIM / 4)      // 256 float4 per row
#define SNUM 5
#define EPSL 1e-6f
#define MARGINL 1.0f
#define WAVES_PER_BLK 4    // one wave per anchor
#define FIXSCALE 4294967296.0  // 2^32

__device__ __forceinline__ float sq4(const float4& x, const float4& y) {
    float dx = x.x - y.x + EPSL;
    float dy = x.y - y.y + EPSL;
    float dz = x.z - y.z + EPSL;
    float dw = x.w - y.w + EPSL;
    return dx * dx + dy * dy + dz * dz + dw * dw;
}

// One wave (64 lanes) per anchor. SLICE-MAJOR: outer loop walks the 4 float4
// slices of the D=1024 row, inner loop the 5 negatives — so only one slice of
// vk/ak is live at a time (~30 VGPRs, no spill; R3's anchor-major order kept
// 51+ floats live and spilled to scratch at VGPR_Count=32 -> 46us).
__global__ __launch_bounds__(256) void hinge_kernel(const float* __restrict__ vfeat,
                                                    const float* __restrict__ afeat,
                                                    unsigned long long* __restrict__ sum_fx,
                                                    unsigned int* __restrict__ done_ctr,
                                                    float* __restrict__ out,
                                                    int B, int nblocks) {
    // XCD-chunked bijective swizzle: each XCD owns a contiguous anchor range so
    // neighbor rows k+1..k+5 are re-read from its own L2.
    int b = blockIdx.x;
    if ((nblocks & 7) == 0) {
        const int chunk = nblocks >> 3;
        b = (b & 7) * chunk + (b >> 3);
    }
    const int wave = threadIdx.x >> 6;
    const int lane = threadIdx.x & 63;
    const int k = b * WAVES_PER_BLK + wave;

    // wave-uniform negative indices
    int j[SNUM];
    #pragma unroll
    for (int m = 0; m < SNUM; ++m) {
        int t = k + m + 1;
        if (m == k) t = k + 1;           // reference's m==k special case (k<SNUM only)
        if (t >= B) t -= B;
        j[m] = t;
    }

    const float4* __restrict__ v4 = reinterpret_cast<const float4*>(vfeat);
    const float4* __restrict__ a4 = reinterpret_cast<const float4*>(afeat);

    float acc[11];
    #pragma unroll
    for (int i = 0; i < 11; ++i) acc[i] = 0.0f;

    #pragma unroll
    for (int s = 0; s < 4; ++s) {
        const int off = s * 64 + lane;
        const float4 vk = v4[(size_t)k * D4 + off];
        const float4 ak = a4[(size_t)k * D4 + off];
        acc[0] += sq4(vk, ak);
        #pragma unroll
        for (int m = 0; m < SNUM; ++m) {
            const float4 aj = a4[(size_t)j[m] * D4 + off];
            const float4 vj = v4[(size_t)j[m] * D4 + off];
            acc[1 + m]        += sq4(vk, aj);   // d_n1 partial
            acc[1 + SNUM + m] += sq4(ak, vj);   // d_n2 partial
        }
    }

    // 64-lane butterfly reduction of the 11 partials
    #pragma unroll
    for (int off = 32; off > 0; off >>= 1) {
        #pragma unroll
        for (int i = 0; i < 11; ++i)
            acc[i] += __shfl_xor(acc[i], off, 64);
    }

    __shared__ float sh[WAVES_PER_BLK];
    if (lane == 0) {
        const float d_p = sqrtf(acc[0]);
        float dn1 = sqrtf(acc[1]);
        float dn2 = sqrtf(acc[1 + SNUM]);
        #pragma unroll
        for (int m = 1; m < SNUM; ++m) {
            dn1 = fminf(dn1, sqrtf(acc[1 + m]));
            dn2 = fminf(dn2, sqrtf(acc[1 + SNUM + m]));
        }
        sh[wave] = fmaxf(MARGINL + 2.0f * d_p - dn1 - dn2, 0.0f);
    }
    __syncthreads();

    if (threadIdx.x == 0) {
        float bsum = 0.0f;
        #pragma unroll
        for (int w = 0; w < WAVES_PER_BLK; ++w) bsum += sh[w];
        // deterministic fixed-point accumulate (integer adds commute exactly)
        unsigned long long fx = (unsigned long long)((double)bsum * FIXSCALE + 0.5);
        atomicAdd(sum_fx, fx);
        __threadfence();
        unsigned int old = atomicAdd(done_ctr, 1u);
        if (old == (unsigned int)(nblocks - 1)) {
            unsigned long long total = atomicAdd(sum_fx, 0ull);  // coherent read
            out[0] = (float)(((double)total / FIXSCALE) / (double)B);
        }
    }
}

extern "C" void kernel_launch(void* const* d_in, const int* in_sizes, int n_in,
                              void* d_out, int out_size, void* d_ws, size_t ws_size,
                              hipStream_t stream) {
    const float* vfeat = (const float*)d_in[0];
    const float* afeat = (const float*)d_in[1];
    const int B = in_sizes[0] / DIM;
    const int nblocks = B / WAVES_PER_BLK;

    unsigned long long* sum_fx = (unsigned long long*)d_ws;
    unsigned int* done_ctr = (unsigned int*)((char*)d_ws + 8);
    float* out = (float*)d_out;

    // zero the 16-byte accumulator region each call (graph-capturable memset node)
    hipMemsetAsync(d_ws, 0, 16, stream);

    hinge_kernel<<<nblocks, 256, 0, stream>>>(vfeat, afeat, sum_fx, done_ctr, out,
                                              B, nblocks);
}